// Round 6
// baseline (657.238 us; speedup 1.0000x reference)
//
#include <hip/hip_runtime.h>

typedef _Float16 half8 __attribute__((ext_vector_type(8)));
typedef float floatx4 __attribute__((ext_vector_type(4)));
typedef unsigned uint4v __attribute__((ext_vector_type(4)));

#define Bsz 512
#define Tsz 168
#define Fsz 16
#define Hsz 256
#define KTILES 9      // K = 288 = 9 * 32  (256 h + 16 x + 16 zero pad)
#define LDS_K 296     // padded LDS row stride in halves

// workspace layout (bytes, all 16B aligned)
#define WSW_OFF   0          // swizzled [w_hh|w_ih|0] f16 frags: 64nt*9kt*64lane*16B = 589824
#define BIAS_OFF  589824     // reordered (b_ih+b_hh) fp32: 1024*4 = 4096
#define HH_OFF    675840     // h history f16 [B][T][H]: 512*168*256*2 = 44040192
#define XBUF_OFF  (HH_OFF + 44040192)   // tagged ring: 32bb*2*16m*128slot*8B = 1 MB

// ---------------- prep: lstm weight swizzle + bias (f16 frag table) --------
__global__ __launch_bounds__(256) void k_prep(
    const float* __restrict__ w_hh, const float* __restrict__ w_ih,
    const float* __restrict__ b_ih, const float* __restrict__ b_hh,
    _Float16* __restrict__ wsw, float* __restrict__ bias) {
    const int b = blockIdx.x, tid = threadIdx.x;
    const int lane = tid & 63, sub = tid >> 6;
    if (b < 144) {                         // w_hh|w_ih swizzle: 576 tiles
        int tile = b * 4 + sub;            // nt*9 + kt
        int nt = tile / KTILES, kt = tile - nt * KTILES;
        int n_in = lane & 15, kg = lane >> 4;
        int J = nt >> 2, g = nt & 3;
        int n_orig = g * 256 + J * 16 + n_in;
        half8 v;
#pragma unroll
        for (int e = 0; e < 8; ++e) {
            int k = kt * 32 + kg * 8 + e;
            float f;
            if (k < 256)      f = w_hh[n_orig * 256 + k];
            else if (k < 272) f = w_ih[n_orig * 16 + (k - 256)];
            else              f = 0.0f;
            v[e] = (_Float16)f;
        }
        ((half8*)wsw)[tile * 64 + lane] = v;
    } else {                               // bias reorder: 1024
        int id = (b - 144) * 256 + tid;
        int nt = id >> 4, n = id & 15;
        int J = nt >> 2, g = nt & 3;
        int n_orig = g * 256 + J * 16 + n;
        bias[id] = b_ih[n_orig] + b_hh[n_orig];
    }
}

// ---------------- recurrent LSTM v18: 2 batch-blocks/WG, RT-hiding ---------
// R17 post-mortem: exchange RT + skew (~3000cy) dominates the 4890cy step;
// compute halving (v17) made things WORSE (more partners = more tail).
// v18 keeps v14's proven per-block body (342us) but each WG owns TWO
// independent batch-blocks (bbA=2p, bbB=2p+1), same ng quarter, same weight
// frags (reused). Schedule: MFMA_A,cell_A,publish_A | MFMA_B,cell_B,
// publish_B | poll_A | poll_B. The publish_A->poll_A window now contains
// the whole B-phase (~1100cy): the exchange RT hides under real work.
// Deadlock-free: every WG publishes BOTH blocks before polling anything.
// 64 WGs (16 pairs x 4 ng); partners blockIdx p+16k are XCD-colocated
// ((p+16k)%8 == p%8) — perf heuristic only, correctness via agent atomics.
__global__ __launch_bounds__(512, 1) void k_lstm18(
    const float* __restrict__ x, const _Float16* __restrict__ wsw,
    const float* __restrict__ bias, unsigned* __restrict__ hh32,
    unsigned long long* __restrict__ xbuf) {
    __shared__ __align__(16) _Float16 hA[16][LDS_K];      // bbA: h | x | pad
    __shared__ __align__(16) _Float16 hB[16][LDS_K];      // bbB: h | x | pad
    __shared__ float gA[4][16][68];                       // bbA gates
    __shared__ float gB[4][16][68];                       // bbB gates

    const int tid = threadIdx.x;
    const int wave = tid >> 6, lane = tid & 63;
    const int n_in = lane & 15, quad = lane >> 4;
    const int p = blockIdx.x & 15, ng = blockIdx.x >> 4;  // 64 WGs
    const int bbA = 2 * p, bbB = 2 * p + 1;
    const int b0A = bbA * 16, b0B = bbB * 16;
    const int Jl = wave & 3;               // local J-block 0..3
    const int gp = wave >> 2;              // gate pair: 0 -> (i,f), 1 -> (g,o)

    // ---- per-wave weight frags + bias (v14 behavior: compiler may sink
    //      reloads to L2; that was the measured-fast configuration) ----
    float bs[2];
    half8 wf[2][KTILES];
#pragma unroll
    for (int gg = 0; gg < 2; ++gg) {
        const int nt = ng * 16 + Jl * 4 + gp * 2 + gg;
        bs[gg] = bias[nt * 16 + n_in];
#pragma unroll
        for (int kt = 0; kt < KTILES; ++kt)
            wf[gg][kt] = ((const half8*)wsw)[((size_t)nt * KTILES + kt) * 64 + lane];
    }

    // zero h0 + x + pad for both blocks, stage x_0
    for (int i = tid; i < 16 * LDS_K; i += 512) {
        ((_Float16*)hA)[i] = (_Float16)0.0f;
        ((_Float16*)hB)[i] = (_Float16)0.0f;
    }
    __syncthreads();
    {
        int m = (tid & 255) >> 4, f = tid & 15;
        if (tid < 256) hA[m][Hsz + f] = (_Float16)x[((b0A + m) * Tsz + 0) * Fsz + f];
        else           hB[m][Hsz + f] = (_Float16)x[((b0B + m) * Tsz + 0) * Fsz + f];
    }
    __syncthreads();

    // cell/publish/gather ownership: thread -> (m = tid>>5, slot = tid&31)
    const int cm = tid >> 5, cj = tid & 31;
    float cA[2] = {0.f, 0.f}, cB[2] = {0.f, 0.f};

    for (int t = 0; t < Tsz; ++t) {
        // ---- x_{t+1} prefetch for both blocks (cold HBM miss hides) ----
        float xr = 0.0f;
        if (t + 1 < Tsz) {
            int m = (tid & 255) >> 4, f = tid & 15;
            xr = (tid < 256)
                ? x[((b0A + m) * Tsz + (t + 1)) * Fsz + f]
                : x[((b0B + m) * Tsz + (t + 1)) * Fsz + f];
        }

        // ================= A-phase =================
        {
            half8 afr[KTILES];
#pragma unroll
            for (int kt = 0; kt < KTILES; ++kt)
                afr[kt] = *(const half8*)&hA[n_in][kt * 32 + quad * 8];
            floatx4 acc[2] = {(floatx4){0.f,0.f,0.f,0.f}, (floatx4){0.f,0.f,0.f,0.f}};
#pragma unroll
            for (int gg = 0; gg < 2; ++gg)
#pragma unroll
                for (int kt = 0; kt < KTILES; ++kt)
                    acc[gg] = __builtin_amdgcn_mfma_f32_16x16x32_f16(
                        afr[kt], wf[gg][kt], acc[gg], 0, 0, 0);
#pragma unroll
            for (int gg = 0; gg < 2; ++gg)
#pragma unroll
                for (int r = 0; r < 4; ++r)
                    gA[gp * 2 + gg][quad * 4 + r][Jl * 16 + n_in] = acc[gg][r] + bs[gg];
        }
        __syncthreads();   // B1: gA staged; hA afr reads done -> hA writable

        // cell A + publish A (gets the store into the fabric ASAP)
        {
            union { _Float16 f[2]; unsigned u; } pk;
#pragma unroll
            for (int e = 0; e < 2; ++e) {
                int jl = 2 * cj + e;
                float ig = gA[0][cm][jl], fg = gA[1][cm][jl];
                float gv = gA[2][cm][jl], og = gA[3][cm][jl];
                float si = 1.0f / (1.0f + __expf(-ig));
                float sf = 1.0f / (1.0f + __expf(-fg));
                float tg = 1.0f - 2.0f / (__expf(2.0f * gv) + 1.0f);
                float so = 1.0f / (1.0f + __expf(-og));
                float c = sf * cA[e] + si * tg;
                cA[e] = c;
                float th = 1.0f - 2.0f / (__expf(2.0f * c) + 1.0f);
                pk.f[e] = (_Float16)(so * th);
            }
            const size_t rbA = (size_t)((bbA * 2 + (t & 1)) * 16);
            if (t + 1 < Tsz) {
                unsigned long long pv = ((unsigned long long)pk.u << 32) | (unsigned)(t + 1);
                __hip_atomic_store(&xbuf[(rbA + cm) * 128 + ng * 32 + cj], pv,
                                   __ATOMIC_RELAXED, __HIP_MEMORY_SCOPE_AGENT);
            }
            *(unsigned*)&hA[cm][ng * 64 + 2 * cj] = pk.u;
            __builtin_nontemporal_store(
                pk.u, &hh32[((size_t)(b0A + cm) * Tsz + t) * 128 + ng * 32 + cj]);
        }

        // ================= B-phase (RT window for A's partners) =========
        {
            half8 afr[KTILES];
#pragma unroll
            for (int kt = 0; kt < KTILES; ++kt)
                afr[kt] = *(const half8*)&hB[n_in][kt * 32 + quad * 8];
            floatx4 acc[2] = {(floatx4){0.f,0.f,0.f,0.f}, (floatx4){0.f,0.f,0.f,0.f}};
#pragma unroll
            for (int gg = 0; gg < 2; ++gg)
#pragma unroll
                for (int kt = 0; kt < KTILES; ++kt)
                    acc[gg] = __builtin_amdgcn_mfma_f32_16x16x32_f16(
                        afr[kt], wf[gg][kt], acc[gg], 0, 0, 0);
#pragma unroll
            for (int gg = 0; gg < 2; ++gg)
#pragma unroll
                for (int r = 0; r < 4; ++r)
                    gB[gp * 2 + gg][quad * 4 + r][Jl * 16 + n_in] = acc[gg][r] + bs[gg];
        }
        __syncthreads();   // B2: gB staged; hB afr reads done -> hB writable

        // cell B + publish B
        {
            union { _Float16 f[2]; unsigned u; } pk;
#pragma unroll
            for (int e = 0; e < 2; ++e) {
                int jl = 2 * cj + e;
                float ig = gB[0][cm][jl], fg = gB[1][cm][jl];
                float gv = gB[2][cm][jl], og = gB[3][cm][jl];
                float si = 1.0f / (1.0f + __expf(-ig));
                float sf = 1.0f / (1.0f + __expf(-fg));
                float tg = 1.0f - 2.0f / (__expf(2.0f * gv) + 1.0f);
                float so = 1.0f / (1.0f + __expf(-og));
                float c = sf * cB[e] + si * tg;
                cB[e] = c;
                float th = 1.0f - 2.0f / (__expf(2.0f * c) + 1.0f);
                pk.f[e] = (_Float16)(so * th);
            }
            const size_t rbB = (size_t)((bbB * 2 + (t & 1)) * 16);
            if (t + 1 < Tsz) {
                unsigned long long pv = ((unsigned long long)pk.u << 32) | (unsigned)(t + 1);
                __hip_atomic_store(&xbuf[(rbB + cm) * 128 + ng * 32 + cj], pv,
                                   __ATOMIC_RELAXED, __HIP_MEMORY_SCOPE_AGENT);
            }
            *(unsigned*)&hB[cm][ng * 64 + 2 * cj] = pk.u;
            __builtin_nontemporal_store(
                pk.u, &hh32[((size_t)(b0B + cm) * Tsz + t) * 128 + ng * 32 + cj]);
        }

        if (t + 1 < Tsz) {
            const unsigned want = (unsigned)(t + 1);
            // ---- poll A partners (their publish_A had the whole B-phase) --
            {
                const size_t rbA = (size_t)((bbA * 2 + (t & 1)) * 16);
                unsigned long long* p1 = &xbuf[(rbA + cm) * 128 + ((ng + 1) & 3) * 32 + cj];
                unsigned long long* p2 = &xbuf[(rbA + cm) * 128 + ((ng + 2) & 3) * 32 + cj];
                unsigned long long* p3 = &xbuf[(rbA + cm) * 128 + ((ng + 3) & 3) * 32 + cj];
                unsigned long long v1 = __hip_atomic_load(p1, __ATOMIC_RELAXED, __HIP_MEMORY_SCOPE_AGENT);
                unsigned long long v2 = __hip_atomic_load(p2, __ATOMIC_RELAXED, __HIP_MEMORY_SCOPE_AGENT);
                unsigned long long v3 = __hip_atomic_load(p3, __ATOMIC_RELAXED, __HIP_MEMORY_SCOPE_AGENT);
                while ((unsigned)v1 != want || (unsigned)v2 != want || (unsigned)v3 != want) {
                    v1 = __hip_atomic_load(p1, __ATOMIC_RELAXED, __HIP_MEMORY_SCOPE_AGENT);
                    v2 = __hip_atomic_load(p2, __ATOMIC_RELAXED, __HIP_MEMORY_SCOPE_AGENT);
                    v3 = __hip_atomic_load(p3, __ATOMIC_RELAXED, __HIP_MEMORY_SCOPE_AGENT);
                }
                *(unsigned*)&hA[cm][((ng + 1) & 3) * 64 + 2 * cj] = (unsigned)(v1 >> 32);
                *(unsigned*)&hA[cm][((ng + 2) & 3) * 64 + 2 * cj] = (unsigned)(v2 >> 32);
                *(unsigned*)&hA[cm][((ng + 3) & 3) * 64 + 2 * cj] = (unsigned)(v3 >> 32);
            }
            // ---- poll B partners (window = poll_A + staging) -------------
            {
                const size_t rbB = (size_t)((bbB * 2 + (t & 1)) * 16);
                unsigned long long* p1 = &xbuf[(rbB + cm) * 128 + ((ng + 1) & 3) * 32 + cj];
                unsigned long long* p2 = &xbuf[(rbB + cm) * 128 + ((ng + 2) & 3) * 32 + cj];
                unsigned long long* p3 = &xbuf[(rbB + cm) * 128 + ((ng + 3) & 3) * 32 + cj];
                unsigned long long v1 = __hip_atomic_load(p1, __ATOMIC_RELAXED, __HIP_MEMORY_SCOPE_AGENT);
                unsigned long long v2 = __hip_atomic_load(p2, __ATOMIC_RELAXED, __HIP_MEMORY_SCOPE_AGENT);
                unsigned long long v3 = __hip_atomic_load(p3, __ATOMIC_RELAXED, __HIP_MEMORY_SCOPE_AGENT);
                while ((unsigned)v1 != want || (unsigned)v2 != want || (unsigned)v3 != want) {
                    v1 = __hip_atomic_load(p1, __ATOMIC_RELAXED, __HIP_MEMORY_SCOPE_AGENT);
                    v2 = __hip_atomic_load(p2, __ATOMIC_RELAXED, __HIP_MEMORY_SCOPE_AGENT);
                    v3 = __hip_atomic_load(p3, __ATOMIC_RELAXED, __HIP_MEMORY_SCOPE_AGENT);
                }
                *(unsigned*)&hB[cm][((ng + 1) & 3) * 64 + 2 * cj] = (unsigned)(v1 >> 32);
                *(unsigned*)&hB[cm][((ng + 2) & 3) * 64 + 2 * cj] = (unsigned)(v2 >> 32);
                *(unsigned*)&hB[cm][((ng + 3) & 3) * 64 + 2 * cj] = (unsigned)(v3 >> 32);
            }
            // stage x_{t+1}
            {
                int m = (tid & 255) >> 4, f = tid & 15;
                if (tid < 256) hA[m][Hsz + f] = (_Float16)xr;
                else           hB[m][Hsz + f] = (_Float16)xr;
            }
            __syncthreads();   // B3: hA/hB fully staged for t+1
        }
    }
}

// ---------------- MLP head v6: in-kernel weight swizzle + peeled pipeline --
// (unchanged — residue ~78us constant across mlp4/5/6; revisit after lstm)
__global__ __launch_bounds__(512, 2) void k_mlp6(
    const _Float16* __restrict__ hh, const float* __restrict__ fc1_w,
    const float* __restrict__ fc2_w, const float* __restrict__ b1,
    const float* __restrict__ b2, const float* __restrict__ w3,
    const float* __restrict__ b3, float* __restrict__ out) {
    __shared__ __align__(16) _Float16 w1sh[64 * 512];   // 64 KB
    __shared__ __align__(16) _Float16 w2sh[16 * 512];   // 16 KB
    __shared__ _Float16 st1[8][16][136];
    __shared__ _Float16 st2[8][16][72];

    const int tid = threadIdx.x;
    const int wave = tid >> 6, lane = tid & 63;
    const int n_in = lane & 15, quad = lane >> 4;

    {   // build fragment tables directly from fc1_w/fc2_w
#pragma unroll
        for (int it = 0; it < 8; ++it) {
            int s = it * 512 + tid;            // s = tile*64 + ln
            int tile = s >> 6, ln = s & 63;
            int nt = tile >> 3, kt = tile & 7, ni = ln & 15, kg = ln >> 4;
            const float* src = &fc1_w[(nt * 16 + ni) * 256 + kt * 32 + kg * 8];
            half8 v;
#pragma unroll
            for (int e = 0; e < 8; ++e) v[e] = (_Float16)src[e];
            ((half8*)w1sh)[s] = v;
        }
#pragma unroll
        for (int it = 0; it < 2; ++it) {
            int s = it * 512 + tid;
            int tile = s >> 6, ln = s & 63;
            int nt = tile >> 2, kt = tile & 3, ni = ln & 15, kg = ln >> 4;
            const float* src = &fc2_w[(nt * 16 + ni) * 128 + kt * 32 + kg * 8];
            half8 v;
#pragma unroll
            for (int e = 0; e < 8; ++e) v[e] = (_Float16)src[e];
            ((half8*)w2sh)[s] = v;
        }
    }
    __syncthreads();

    uint4v bufA[8], bufB[8], bufC[8];
    const int ch0 = blockIdx.x, ch1 = blockIdx.x + 224, ch2 = blockIdx.x + 448;

#define MLP_LOAD(dst, ch)                                                      \
    {                                                                          \
        const int tok0_ = (ch) * 128 + wave * 16;                              \
        _Pragma("unroll")                                                      \
        for (int kt = 0; kt < 8; ++kt)                                         \
            dst[kt] = __builtin_nontemporal_load(                              \
                (const uint4v*)&hh[(size_t)(tok0_ + n_in) * 256 + kt * 32 +    \
                                   quad * 8]);                                 \
    }

    MLP_LOAD(bufA, ch0)
    MLP_LOAD(bufB, ch1)
    MLP_LOAD(bufC, ch2)

    auto compute = [&](const uint4v* raw, int chunk) {
        const int tok0 = chunk * 128 + wave * 16;
        half8 afr[8];
#pragma unroll
        for (int kt = 0; kt < 8; ++kt)
            afr[kt] = __builtin_bit_cast(half8, raw[kt]);

#pragma unroll
        for (int nt = 0; nt < 8; ++nt) {
            floatx4 a = (floatx4){0.f, 0.f, 0.f, 0.f};
#pragma unroll
            for (int kt = 0; kt < 8; ++kt) {
                half8 bfr = *(const half8*)&w1sh[(nt * 8 + kt) * 512 + lane * 8];
                a = __builtin_amdgcn_mfma_f32_16x16x32_f16(afr[kt], bfr, a, 0, 0, 0);
            }
            float bbv = b1[nt * 16 + n_in];
#pragma unroll
            for (int r = 0; r < 4; ++r) {
                float v = a[r] + bbv;
                st1[wave][quad * 4 + r][nt * 16 + n_in] = (_Float16)(v > 0.f ? v : 0.f);
            }
        }

        half8 a2[4];
#pragma unroll
        for (int kt = 0; kt < 4; ++kt)
            a2[kt] = *(const half8*)&st1[wave][n_in][kt * 32 + quad * 8];
#pragma unroll
        for (int nt = 0; nt < 4; ++nt) {
            floatx4 a = (floatx4){0.f, 0.f, 0.f, 0.f};
#pragma unroll
            for (int kt = 0; kt < 4; ++kt) {
                half8 bfr = *(const half8*)&w2sh[(nt * 4 + kt) * 512 + lane * 8];
                a = __builtin_amdgcn_mfma_f32_16x16x32_f16(a2[kt], bfr, a, 0, 0, 0);
            }
            float bbv = b2[nt * 16 + n_in];
#pragma unroll
            for (int r = 0; r < 4; ++r) {
                float v = a[r] + bbv;
                st2[wave][quad * 4 + r][nt * 16 + n_in] = (_Float16)(v > 0.f ? v : 0.f);
            }
        }

        float p = 0.0f;
#pragma unroll
        for (int e = 0; e < 16; ++e)
            p += (float)st2[wave][n_in][quad * 16 + e] * w3[quad * 16 + e];
        p += __shfl_down(p, 32);
        p += __shfl_down(p, 16);
        if (quad == 0) out[tok0 + n_in] = p + b3[0];
    };

    compute(bufA, ch0);
    compute(bufB, ch1);
    compute(bufC, ch2);
#undef MLP_LOAD
}

extern "C" void kernel_launch(void* const* d_in, const int* in_sizes, int n_in,
                              void* d_out, int out_size, void* d_ws, size_t ws_size,
                              hipStream_t stream) {
    const float* x     = (const float*)d_in[0];
    const float* w_ih  = (const float*)d_in[1];
    const float* w_hh  = (const float*)d_in[2];
    const float* b_ih  = (const float*)d_in[3];
    const float* b_hh  = (const float*)d_in[4];
    const float* fc1_w = (const float*)d_in[5];
    const float* fc1_b = (const float*)d_in[6];
    const float* fc2_w = (const float*)d_in[7];
    const float* fc2_b = (const float*)d_in[8];
    const float* fc3_w = (const float*)d_in[9];
    const float* fc3_b = (const float*)d_in[10];

    char* ws = (char*)d_ws;
    _Float16* wsw  = (_Float16*)(ws + WSW_OFF);
    float*    bias = (float*)(ws + BIAS_OFF);
    _Float16* hhist= (_Float16*)(ws + HH_OFF);
    unsigned long long* xbuf = (unsigned long long*)(ws + XBUF_OFF);

    k_prep<<<148, 256, 0, stream>>>(w_hh, w_ih, b_ih, b_hh, wsw, bias);
    k_lstm18<<<64, 512, 0, stream>>>(x, wsw, bias, (unsigned*)hhist, xbuf);
    k_mlp6<<<224, 512, 0, stream>>>(hhist, fc1_w, fc2_w, fc1_b, fc2_b,
                                    fc3_w, fc3_b, (float*)d_out);
}

// Round 8
// 558.700 us; speedup vs baseline: 1.1764x; 1.1764x over previous
//
#include <hip/hip_runtime.h>

typedef _Float16 half8 __attribute__((ext_vector_type(8)));
typedef float floatx4 __attribute__((ext_vector_type(4)));
typedef unsigned uint4v __attribute__((ext_vector_type(4)));

#define Bsz 512
#define Tsz 168
#define Fsz 16
#define Hsz 256
#define KTILES 9      // K = 288 = 9 * 32  (256 h + 16 x + 16 zero pad)
#define LDS_K 296     // padded LDS row stride in halves

// workspace layout (bytes, all 16B aligned)
#define WSW_OFF   0          // swizzled [w_hh|w_ih|0] f16 frags: 64nt*9kt*64lane*16B = 589824
#define BIAS_OFF  589824     // reordered (b_ih+b_hh) fp32: 1024*4 = 4096
#define HH_OFF    675840     // h history f16 [B][T][H]: 512*168*256*2 = 44040192
#define XBUF_OFF  (HH_OFF + 44040192)   // tagged ring: 32bb*2*16m*128slot*8B = 1 MB

// ---------------- prep: lstm weight swizzle + bias (f16 frag table) --------
__global__ __launch_bounds__(256) void k_prep(
    const float* __restrict__ w_hh, const float* __restrict__ w_ih,
    const float* __restrict__ b_ih, const float* __restrict__ b_hh,
    _Float16* __restrict__ wsw, float* __restrict__ bias) {
    const int b = blockIdx.x, tid = threadIdx.x;
    const int lane = tid & 63, sub = tid >> 6;
    if (b < 144) {                         // w_hh|w_ih swizzle: 576 tiles
        int tile = b * 4 + sub;            // nt*9 + kt
        int nt = tile / KTILES, kt = tile - nt * KTILES;
        int n_in = lane & 15, kg = lane >> 4;
        int J = nt >> 2, g = nt & 3;
        int n_orig = g * 256 + J * 16 + n_in;
        half8 v;
#pragma unroll
        for (int e = 0; e < 8; ++e) {
            int k = kt * 32 + kg * 8 + e;
            float f;
            if (k < 256)      f = w_hh[n_orig * 256 + k];
            else if (k < 272) f = w_ih[n_orig * 16 + (k - 256)];
            else              f = 0.0f;
            v[e] = (_Float16)f;
        }
        ((half8*)wsw)[tile * 64 + lane] = v;
    } else {                               // bias reorder: 1024
        int id = (b - 144) * 256 + tid;
        int nt = id >> 4, n = id & 15;
        int J = nt >> 2, g = nt & 3;
        int n_orig = g * 256 + J * 16 + n;
        bias[id] = b_ih[n_orig] + b_hh[n_orig];
    }
}

// ---------------- recurrent LSTM v19: v14-exact + asm weight prefetch ------
// R18 post-mortem: serializing 2 blocks/WG doubled the serial chain (588us);
// wall = steps x step-time, RT can't hide under same-chain work. Back to
// v14's exact 342us body. v14 budget: VALU 780 + MFMA 250 + L2 weight
// stream 1300 + exchange RT 2200-2500 + syncs — and the weight stream is
// SERIALIZED after the poll window because the compiler sinks the wf loads
// to their use (proven R14/R15/R16; pins get spill-satisfied). v19: the 18
// frag loads are issued as asm volatile global_load_dwordx4 INSIDE the poll
// window (after NT store, before polls). Volatile asm can't be sunk or
// remat'd -> the ~1300cy L2 drain overlaps the poll RT. Sync: vmcnt retires
// in issue order; the polls (issued after) are consumed with a compiler
// waitcnt, which necessarily drains the older weight loads first -> wf is
// complete before next step's MFMA. Values identical every step, so per-
// iter redefinition is correct (no double buffer).
// (R7 was broker infra failure — same signature as R3; resubmit unchanged.)
#define WPREFETCH()                                                            \
    asm volatile(                                                              \
        "global_load_dwordx4 %0, %18, off\n\t"                                 \
        "global_load_dwordx4 %1, %18, off offset:1024\n\t"                     \
        "global_load_dwordx4 %2, %18, off offset:2048\n\t"                     \
        "global_load_dwordx4 %3, %18, off offset:3072\n\t"                     \
        "global_load_dwordx4 %4, %19, off\n\t"                                 \
        "global_load_dwordx4 %5, %19, off offset:1024\n\t"                     \
        "global_load_dwordx4 %6, %19, off offset:2048\n\t"                     \
        "global_load_dwordx4 %7, %19, off offset:3072\n\t"                     \
        "global_load_dwordx4 %8, %20, off\n\t"                                 \
        "global_load_dwordx4 %9, %21, off\n\t"                                 \
        "global_load_dwordx4 %10, %21, off offset:1024\n\t"                    \
        "global_load_dwordx4 %11, %21, off offset:2048\n\t"                    \
        "global_load_dwordx4 %12, %21, off offset:3072\n\t"                    \
        "global_load_dwordx4 %13, %22, off\n\t"                                \
        "global_load_dwordx4 %14, %22, off offset:1024\n\t"                    \
        "global_load_dwordx4 %15, %22, off offset:2048\n\t"                    \
        "global_load_dwordx4 %16, %22, off offset:3072\n\t"                    \
        "global_load_dwordx4 %17, %23, off\n\t"                                \
        : "=&v"(wf[0][0]), "=&v"(wf[0][1]), "=&v"(wf[0][2]), "=&v"(wf[0][3]),  \
          "=&v"(wf[0][4]), "=&v"(wf[0][5]), "=&v"(wf[0][6]), "=&v"(wf[0][7]),  \
          "=&v"(wf[0][8]), "=&v"(wf[1][0]), "=&v"(wf[1][1]), "=&v"(wf[1][2]),  \
          "=&v"(wf[1][3]), "=&v"(wf[1][4]), "=&v"(wf[1][5]), "=&v"(wf[1][6]),  \
          "=&v"(wf[1][7]), "=&v"(wf[1][8])                                     \
        : "v"(a00), "v"(a01), "v"(a02), "v"(a10), "v"(a11), "v"(a12))

__global__ __launch_bounds__(512, 1) void k_lstm19(
    const float* __restrict__ x, const _Float16* __restrict__ wsw,
    const float* __restrict__ bias, unsigned* __restrict__ hh32,
    unsigned long long* __restrict__ xbuf) {
    __shared__ __align__(16) _Float16 h_lds[16][LDS_K];   // h | x | pad
    __shared__ float glds[4][16][68];                     // [gate][m][j_local], pad 68

    const int tid = threadIdx.x;
    const int wave = tid >> 6, lane = tid & 63;
    const int n_in = lane & 15, quad = lane >> 4;
    const int bb = blockIdx.x & 31, ng = blockIdx.x >> 5;   // XCD-colocated swizzle
    const int b0 = bb * 16;
    const int Jl = wave & 3;               // local J-block 0..3
    const int gp = wave >> 2;              // gate pair: 0 -> (i,f), 1 -> (g,o)

    // ---- weight frag addresses (loop-invariant) + bias ----
    // frag byte addr = wsw + nt*9216 + kt*1024 + lane*16; kt split 0-3/4-7/8
    const int nt0 = ng * 16 + Jl * 4 + gp * 2 + 0;
    const int nt1 = ng * 16 + Jl * 4 + gp * 2 + 1;
    const char* wb = (const char*)wsw;
    unsigned long long a00 = (unsigned long long)(wb + nt0 * 9216 + lane * 16);
    unsigned long long a01 = a00 + 4096;
    unsigned long long a02 = a00 + 8192;
    unsigned long long a10 = (unsigned long long)(wb + nt1 * 9216 + lane * 16);
    unsigned long long a11 = a10 + 4096;
    unsigned long long a12 = a10 + 8192;
    float bs[2];
    bs[0] = bias[nt0 * 16 + n_in];
    bs[1] = bias[nt1 * 16 + n_in];

    uint4v wf[2][KTILES];
    WPREFETCH();            // prologue fill; drained before first use

    // zero h0 + x + pad, stage x_0
    for (int i = tid; i < 16 * LDS_K; i += 512)
        ((_Float16*)h_lds)[i] = (_Float16)0.0f;
    __syncthreads();
    if (tid < 256) {
        int m = tid >> 4, f = tid & 15;
        h_lds[m][Hsz + f] = (_Float16)x[((b0 + m) * Tsz + 0) * Fsz + f];
    }
    __syncthreads();

    // cell/publish/gather ownership: thread -> (m = tid>>5, slot = tid&31)
    const int cm = tid >> 5, cj = tid & 31;
    float c_st[2] = {0.f, 0.f};

    for (int t = 0; t < Tsz; ++t) {
        // ---- A-frags from LDS; B-frags from asm-prefetched registers ----
        half8 afr[KTILES];
#pragma unroll
        for (int kt = 0; kt < KTILES; ++kt)
            afr[kt] = *(const half8*)&h_lds[n_in][kt * 32 + quad * 8];

        floatx4 acc[2] = {(floatx4){0.f,0.f,0.f,0.f}, (floatx4){0.f,0.f,0.f,0.f}};
#pragma unroll
        for (int gg = 0; gg < 2; ++gg) {
#pragma unroll
            for (int kt = 0; kt < KTILES; ++kt)
                acc[gg] = __builtin_amdgcn_mfma_f32_16x16x32_f16(
                    afr[kt], __builtin_bit_cast(half8, wf[gg][kt]), acc[gg], 0, 0, 0);
        }

        // ---- stage gate pre-activations to LDS ----
#pragma unroll
        for (int gg = 0; gg < 2; ++gg)
#pragma unroll
            for (int r = 0; r < 4; ++r)
                glds[gp * 2 + gg][quad * 4 + r][Jl * 16 + n_in] = acc[gg][r] + bs[gg];
        __syncthreads();   // G1: gates staged; afr reads done -> h_lds writable

        // ---- cell update: thread owns (cm, j_local = 2cj, 2cj+1) ----
        union { _Float16 f[2]; unsigned u; } pk;
#pragma unroll
        for (int e = 0; e < 2; ++e) {
            int jl = 2 * cj + e;
            float ig = glds[0][cm][jl];
            float fg = glds[1][cm][jl];
            float gg_ = glds[2][cm][jl];
            float og = glds[3][cm][jl];
            float si = 1.0f / (1.0f + __expf(-ig));
            float sf = 1.0f / (1.0f + __expf(-fg));
            float tg = 1.0f - 2.0f / (__expf(2.0f * gg_) + 1.0f);
            float so = 1.0f / (1.0f + __expf(-og));
            float c = sf * c_st[e] + si * tg;
            c_st[e] = c;
            float th = 1.0f - 2.0f / (__expf(2.0f * c) + 1.0f);
            pk.f[e] = (_Float16)(so * th);
        }
        // own quarter of h_{t+1} straight into LDS (safe: reads done at G1)
        *(unsigned*)&h_lds[cm][ng * 64 + 2 * cj] = pk.u;

        const size_t rb = ((size_t)((bb * 2 + (t & 1)) * 16));   // ring base (rows)
        if (t + 1 < Tsz) {
            // publish own slot as a single tagged atom {data | t+1} (L2-resident)
            unsigned long long pv = ((unsigned long long)pk.u << 32) | (unsigned)(t + 1);
            __hip_atomic_store(&xbuf[(rb + cm) * 128 + ng * 32 + cj], pv,
                               __ATOMIC_RELAXED, __HIP_MEMORY_SCOPE_AGENT);
        }
        // history write for k_mlp: NON-TEMPORAL -> no L2 allocate, xbuf survives
        __builtin_nontemporal_store(
            pk.u, &hh32[((size_t)(b0 + cm) * Tsz + t) * 128 + ng * 32 + cj]);

        if (t + 1 < Tsz) {
            // ---- weight prefetch for t+1: issues BEFORE polls, drains
            //      under the exchange RT (the whole point of v19) ----
            WPREFETCH();

            // prefetch x_{t+1}; ack overlaps the polls below
            float xr = 0.0f;
            if (tid < 256)
                xr = x[((b0 + (tid >> 4)) * Tsz + (t + 1)) * Fsz + (tid & 15)];

            // ---- gather 3 partner quarters: CONCURRENT tagged-atom polls ----
            const unsigned want = (unsigned)(t + 1);
            unsigned long long* p1 = &xbuf[(rb + cm) * 128 + ((ng + 1) & 3) * 32 + cj];
            unsigned long long* p2 = &xbuf[(rb + cm) * 128 + ((ng + 2) & 3) * 32 + cj];
            unsigned long long* p3 = &xbuf[(rb + cm) * 128 + ((ng + 3) & 3) * 32 + cj];
            unsigned long long v1 = __hip_atomic_load(p1, __ATOMIC_RELAXED,
                                                      __HIP_MEMORY_SCOPE_AGENT);
            unsigned long long v2 = __hip_atomic_load(p2, __ATOMIC_RELAXED,
                                                      __HIP_MEMORY_SCOPE_AGENT);
            unsigned long long v3 = __hip_atomic_load(p3, __ATOMIC_RELAXED,
                                                      __HIP_MEMORY_SCOPE_AGENT);
            while ((unsigned)v1 != want || (unsigned)v2 != want || (unsigned)v3 != want) {
                if ((unsigned)v1 != want)
                    v1 = __hip_atomic_load(p1, __ATOMIC_RELAXED, __HIP_MEMORY_SCOPE_AGENT);
                if ((unsigned)v2 != want)
                    v2 = __hip_atomic_load(p2, __ATOMIC_RELAXED, __HIP_MEMORY_SCOPE_AGENT);
                if ((unsigned)v3 != want)
                    v3 = __hip_atomic_load(p3, __ATOMIC_RELAXED, __HIP_MEMORY_SCOPE_AGENT);
            }
            *(unsigned*)&h_lds[cm][((ng + 1) & 3) * 64 + 2 * cj] = (unsigned)(v1 >> 32);
            *(unsigned*)&h_lds[cm][((ng + 2) & 3) * 64 + 2 * cj] = (unsigned)(v2 >> 32);
            *(unsigned*)&h_lds[cm][((ng + 3) & 3) * 64 + 2 * cj] = (unsigned)(v3 >> 32);
            if (tid < 256)
                h_lds[tid >> 4][Hsz + (tid & 15)] = (_Float16)xr;
            __syncthreads();   // G4: full h_{t+1} + x_{t+1} staged (drains vmcnt)
        }
    }
}

// ---------------- MLP head v6: in-kernel weight swizzle + peeled pipeline --
// (unchanged — residue ~78us; revisit after lstm)
__global__ __launch_bounds__(512, 2) void k_mlp6(
    const _Float16* __restrict__ hh, const float* __restrict__ fc1_w,
    const float* __restrict__ fc2_w, const float* __restrict__ b1,
    const float* __restrict__ b2, const float* __restrict__ w3,
    const float* __restrict__ b3, float* __restrict__ out) {
    __shared__ __align__(16) _Float16 w1sh[64 * 512];   // 64 KB
    __shared__ __align__(16) _Float16 w2sh[16 * 512];   // 16 KB
    __shared__ _Float16 st1[8][16][136];
    __shared__ _Float16 st2[8][16][72];

    const int tid = threadIdx.x;
    const int wave = tid >> 6, lane = tid & 63;
    const int n_in = lane & 15, quad = lane >> 4;

    {   // build fragment tables directly from fc1_w/fc2_w
#pragma unroll
        for (int it = 0; it < 8; ++it) {
            int s = it * 512 + tid;            // s = tile*64 + ln
            int tile = s >> 6, ln = s & 63;
            int nt = tile >> 3, kt = tile & 7, ni = ln & 15, kg = ln >> 4;
            const float* src = &fc1_w[(nt * 16 + ni) * 256 + kt * 32 + kg * 8];
            half8 v;
#pragma unroll
            for (int e = 0; e < 8; ++e) v[e] = (_Float16)src[e];
            ((half8*)w1sh)[s] = v;
        }
#pragma unroll
        for (int it = 0; it < 2; ++it) {
            int s = it * 512 + tid;
            int tile = s >> 6, ln = s & 63;
            int nt = tile >> 2, kt = tile & 3, ni = ln & 15, kg = ln >> 4;
            const float* src = &fc2_w[(nt * 16 + ni) * 128 + kt * 32 + kg * 8];
            half8 v;
#pragma unroll
            for (int e = 0; e < 8; ++e) v[e] = (_Float16)src[e];
            ((half8*)w2sh)[s] = v;
        }
    }
    __syncthreads();

    uint4v bufA[8], bufB[8], bufC[8];
    const int ch0 = blockIdx.x, ch1 = blockIdx.x + 224, ch2 = blockIdx.x + 448;

#define MLP_LOAD(dst, ch)                                                      \
    {                                                                          \
        const int tok0_ = (ch) * 128 + wave * 16;                              \
        _Pragma("unroll")                                                      \
        for (int kt = 0; kt < 8; ++kt)                                         \
            dst[kt] = __builtin_nontemporal_load(                              \
                (const uint4v*)&hh[(size_t)(tok0_ + n_in) * 256 + kt * 32 +    \
                                   quad * 8]);                                 \
    }

    MLP_LOAD(bufA, ch0)
    MLP_LOAD(bufB, ch1)
    MLP_LOAD(bufC, ch2)

    auto compute = [&](const uint4v* raw, int chunk) {
        const int tok0 = chunk * 128 + wave * 16;
        half8 afr[8];
#pragma unroll
        for (int kt = 0; kt < 8; ++kt)
            afr[kt] = __builtin_bit_cast(half8, raw[kt]);

#pragma unroll
        for (int nt = 0; nt < 8; ++nt) {
            floatx4 a = (floatx4){0.f, 0.f, 0.f, 0.f};
#pragma unroll
            for (int kt = 0; kt < 8; ++kt) {
                half8 bfr = *(const half8*)&w1sh[(nt * 8 + kt) * 512 + lane * 8];
                a = __builtin_amdgcn_mfma_f32_16x16x32_f16(afr[kt], bfr, a, 0, 0, 0);
            }
            float bbv = b1[nt * 16 + n_in];
#pragma unroll
            for (int r = 0; r < 4; ++r) {
                float v = a[r] + bbv;
                st1[wave][quad * 4 + r][nt * 16 + n_in] = (_Float16)(v > 0.f ? v : 0.f);
            }
        }

        half8 a2[4];
#pragma unroll
        for (int kt = 0; kt < 4; ++kt)
            a2[kt] = *(const half8*)&st1[wave][n_in][kt * 32 + quad * 8];
#pragma unroll
        for (int nt = 0; nt < 4; ++nt) {
            floatx4 a = (floatx4){0.f, 0.f, 0.f, 0.f};
#pragma unroll
            for (int kt = 0; kt < 4; ++kt) {
                half8 bfr = *(const half8*)&w2sh[(nt * 4 + kt) * 512 + lane * 8];
                a = __builtin_amdgcn_mfma_f32_16x16x32_f16(a2[kt], bfr, a, 0, 0, 0);
            }
            float bbv = b2[nt * 16 + n_in];
#pragma unroll
            for (int r = 0; r < 4; ++r) {
                float v = a[r] + bbv;
                st2[wave][quad * 4 + r][nt * 16 + n_in] = (_Float16)(v > 0.f ? v : 0.f);
            }
        }

        float p = 0.0f;
#pragma unroll
        for (int e = 0; e < 16; ++e)
            p += (float)st2[wave][n_in][quad * 16 + e] * w3[quad * 16 + e];
        p += __shfl_down(p, 32);
        p += __shfl_down(p, 16);
        if (quad == 0) out[tok0 + n_in] = p + b3[0];
    };

    compute(bufA, ch0);
    compute(bufB, ch1);
    compute(bufC, ch2);
#undef MLP_LOAD
}

extern "C" void kernel_launch(void* const* d_in, const int* in_sizes, int n_in,
                              void* d_out, int out_size, void* d_ws, size_t ws_size,
                              hipStream_t stream) {
    const float* x     = (const float*)d_in[0];
    const float* w_ih  = (const float*)d_in[1];
    const float* w_hh  = (const float*)d_in[2];
    const float* b_ih  = (const float*)d_in[3];
    const float* b_hh  = (const float*)d_in[4];
    const float* fc1_w = (const float*)d_in[5];
    const float* fc1_b = (const float*)d_in[6];
    const float* fc2_w = (const float*)d_in[7];
    const float* fc2_b = (const float*)d_in[8];
    const float* fc3_w = (const float*)d_in[9];
    const float* fc3_b = (const float*)d_in[10];

    char* ws = (char*)d_ws;
    _Float16* wsw  = (_Float16*)(ws + WSW_OFF);
    float*    bias = (float*)(ws + BIAS_OFF);
    _Float16* hhist= (_Float16*)(ws + HH_OFF);
    unsigned long long* xbuf = (unsigned long long*)(ws + XBUF_OFF);

    k_prep<<<148, 256, 0, stream>>>(w_hh, w_ih, b_ih, b_hh, wsw, bias);
    k_lstm19<<<128, 512, 0, stream>>>(x, wsw, bias, (unsigned*)hhist, xbuf);
    k_mlp6<<<224, 512, 0, stream>>>(hhist, fc1_w, fc2_w, fc1_b, fc2_b,
                                    fc3_w, fc3_b, (float*)d_out);
}

// Round 9
// 426.134 us; speedup vs baseline: 1.5423x; 1.3111x over previous
//
#include <hip/hip_runtime.h>

typedef _Float16 half8 __attribute__((ext_vector_type(8)));
typedef float floatx4 __attribute__((ext_vector_type(4)));
typedef unsigned uint4v __attribute__((ext_vector_type(4)));

#define Bsz 512
#define Tsz 168
#define Fsz 16
#define Hsz 256
#define KTILES 9      // K = 288 = 9 * 32  (256 h + 16 x + 16 zero pad)
#define LDS_K 296     // padded LDS row stride in halves

// workspace layout (bytes, all 16B aligned)
#define WSW_OFF   0          // swizzled [w_hh|w_ih|0] f16 frags: 64nt*9kt*64lane*16B = 589824
#define BIAS_OFF  589824     // reordered (b_ih+b_hh) fp32: 1024*4 = 4096
#define HH_OFF    675840     // h history f16 [B][T][H]: 512*168*256*2 = 44040192
#define XBUF_OFF  (HH_OFF + 44040192)   // tagged exchange ring: 32bb*2*16m*128slot*8B = 1 MB

// ---------------- prep: lstm weight swizzle + bias (f16 frag table) --------
// 148 blocks: 144 wsw + 4 bias. (fc swizzles moved in-kernel to k_mlp7.)
__global__ __launch_bounds__(256) void k_prep(
    const float* __restrict__ w_hh, const float* __restrict__ w_ih,
    const float* __restrict__ b_ih, const float* __restrict__ b_hh,
    _Float16* __restrict__ wsw, float* __restrict__ bias) {
    const int b = blockIdx.x, tid = threadIdx.x;
    const int lane = tid & 63, sub = tid >> 6;
    if (b < 144) {                         // w_hh|w_ih swizzle: 576 tiles
        int tile = b * 4 + sub;            // nt*9 + kt
        int nt = tile / KTILES, kt = tile - nt * KTILES;
        int n_in = lane & 15, kg = lane >> 4;
        int J = nt >> 2, g = nt & 3;
        int n_orig = g * 256 + J * 16 + n_in;
        half8 v;
#pragma unroll
        for (int e = 0; e < 8; ++e) {
            int k = kt * 32 + kg * 8 + e;
            float f;
            if (k < 256)      f = w_hh[n_orig * 256 + k];
            else if (k < 272) f = w_ih[n_orig * 16 + (k - 256)];
            else              f = 0.0f;
            v[e] = (_Float16)f;
        }
        ((half8*)wsw)[tile * 64 + lane] = v;
    } else {                               // bias reorder: 1024
        int id = (b - 144) * 256 + tid;
        int nt = id >> 4, n = id & 15;
        int J = nt >> 2, g = nt & 3;
        int n_orig = g * 256 + J * 16 + n;
        bias[id] = b_ih[n_orig] + b_hh[n_orig];
    }
}

// ---------------- recurrent LSTM v14 (CHAMPION, byte-identical) ------------
// Measured 342us (R1). Five structural variants (remat fold, asm pin, 8-way
// split, 2-block pairing, asm weight prefetch) all regressed: the step is
// exchange-RT+skew bound and vmcnt in-order retirement defeats same-chain
// prefetch scheduling (v19: polls serialized behind weight drain, 487us).
// This body is the local optimum of the 4-WG ring topology — do not touch.
__global__ __launch_bounds__(512, 1) void k_lstm14(
    const float* __restrict__ x, const _Float16* __restrict__ wsw,
    const float* __restrict__ bias, unsigned* __restrict__ hh32,
    unsigned long long* __restrict__ xbuf) {
    __shared__ __align__(16) _Float16 h_lds[16][LDS_K];   // h | x | pad
    __shared__ float glds[4][16][68];                     // [gate][m][j_local], pad 68

    const int tid = threadIdx.x;
    const int wave = tid >> 6, lane = tid & 63;
    const int n_in = lane & 15, quad = lane >> 4;
    const int bb = blockIdx.x & 31, ng = blockIdx.x >> 5;   // XCD-colocated swizzle
    const int b0 = bb * 16;
    const int Jl = wave & 3;               // local J-block 0..3
    const int gp = wave >> 2;              // gate pair: 0 -> (i,f), 1 -> (g,o)

    // ---- one-time: this wave's 18 weight B-frags straight into VGPRs ----
    float bs[2];
    half8 wf[2][KTILES];
#pragma unroll
    for (int gg = 0; gg < 2; ++gg) {
        const int nt = ng * 16 + Jl * 4 + gp * 2 + gg;
        bs[gg] = bias[nt * 16 + n_in];
#pragma unroll
        for (int kt = 0; kt < KTILES; ++kt)
            wf[gg][kt] = ((const half8*)wsw)[((size_t)nt * KTILES + kt) * 64 + lane];
    }

    // zero h0 + x + pad, stage x_0
    for (int i = tid; i < 16 * LDS_K; i += 512)
        ((_Float16*)h_lds)[i] = (_Float16)0.0f;
    __syncthreads();
    if (tid < 256) {
        int m = tid >> 4, f = tid & 15;
        h_lds[m][Hsz + f] = (_Float16)x[((b0 + m) * Tsz + 0) * Fsz + f];
    }
    __syncthreads();

    // cell/publish/gather ownership: thread -> (m = tid>>5, slot = tid&31)
    const int cm = tid >> 5, cj = tid & 31;
    float c_st[2] = {0.f, 0.f};

    for (int t = 0; t < Tsz; ++t) {
        // ---- A-frags from LDS; B-frags all from registers ----
        half8 afr[KTILES];
#pragma unroll
        for (int kt = 0; kt < KTILES; ++kt)
            afr[kt] = *(const half8*)&h_lds[n_in][kt * 32 + quad * 8];

        floatx4 acc[2] = {(floatx4){0.f,0.f,0.f,0.f}, (floatx4){0.f,0.f,0.f,0.f}};
#pragma unroll
        for (int gg = 0; gg < 2; ++gg) {
#pragma unroll
            for (int kt = 0; kt < KTILES; ++kt)
                acc[gg] = __builtin_amdgcn_mfma_f32_16x16x32_f16(afr[kt], wf[gg][kt], acc[gg], 0, 0, 0);
        }

        // ---- stage gate pre-activations to LDS ----
#pragma unroll
        for (int gg = 0; gg < 2; ++gg)
#pragma unroll
            for (int r = 0; r < 4; ++r)
                glds[gp * 2 + gg][quad * 4 + r][Jl * 16 + n_in] = acc[gg][r] + bs[gg];
        __syncthreads();   // G1: gates staged; afr reads done -> h_lds writable

        // ---- cell update: thread owns (cm, j_local = 2cj, 2cj+1) ----
        union { _Float16 f[2]; unsigned u; } pk;
#pragma unroll
        for (int e = 0; e < 2; ++e) {
            int jl = 2 * cj + e;
            float ig = glds[0][cm][jl];
            float fg = glds[1][cm][jl];
            float gg_ = glds[2][cm][jl];
            float og = glds[3][cm][jl];
            float si = 1.0f / (1.0f + __expf(-ig));
            float sf = 1.0f / (1.0f + __expf(-fg));
            float tg = 1.0f - 2.0f / (__expf(2.0f * gg_) + 1.0f);
            float so = 1.0f / (1.0f + __expf(-og));
            float c = sf * c_st[e] + si * tg;
            c_st[e] = c;
            float th = 1.0f - 2.0f / (__expf(2.0f * c) + 1.0f);
            pk.f[e] = (_Float16)(so * th);
        }
        // own quarter of h_{t+1} straight into LDS (safe: reads done at G1)
        *(unsigned*)&h_lds[cm][ng * 64 + 2 * cj] = pk.u;

        const size_t rb = ((size_t)((bb * 2 + (t & 1)) * 16));   // ring base (rows)
        if (t + 1 < Tsz) {
            // publish own slot as a single tagged atom {data | t+1} (L2-resident)
            unsigned long long pv = ((unsigned long long)pk.u << 32) | (unsigned)(t + 1);
            __hip_atomic_store(&xbuf[(rb + cm) * 128 + ng * 32 + cj], pv,
                               __ATOMIC_RELAXED, __HIP_MEMORY_SCOPE_AGENT);
        }
        // history write for k_mlp: NON-TEMPORAL -> no L2 allocate, xbuf survives
        __builtin_nontemporal_store(
            pk.u, &hh32[((size_t)(b0 + cm) * Tsz + t) * 128 + ng * 32 + cj]);

        if (t + 1 < Tsz) {
            // prefetch x_{t+1}; ack overlaps the polls below
            float xr = 0.0f;
            if (tid < 256)
                xr = x[((b0 + (tid >> 4)) * Tsz + (t + 1)) * Fsz + (tid & 15)];

            // ---- gather 3 partner quarters: CONCURRENT tagged-atom polls ----
            const unsigned want = (unsigned)(t + 1);
            unsigned long long* p1 = &xbuf[(rb + cm) * 128 + ((ng + 1) & 3) * 32 + cj];
            unsigned long long* p2 = &xbuf[(rb + cm) * 128 + ((ng + 2) & 3) * 32 + cj];
            unsigned long long* p3 = &xbuf[(rb + cm) * 128 + ((ng + 3) & 3) * 32 + cj];
            unsigned long long v1 = __hip_atomic_load(p1, __ATOMIC_RELAXED,
                                                      __HIP_MEMORY_SCOPE_AGENT);
            unsigned long long v2 = __hip_atomic_load(p2, __ATOMIC_RELAXED,
                                                      __HIP_MEMORY_SCOPE_AGENT);
            unsigned long long v3 = __hip_atomic_load(p3, __ATOMIC_RELAXED,
                                                      __HIP_MEMORY_SCOPE_AGENT);
            while ((unsigned)v1 != want || (unsigned)v2 != want || (unsigned)v3 != want) {
                if ((unsigned)v1 != want)
                    v1 = __hip_atomic_load(p1, __ATOMIC_RELAXED, __HIP_MEMORY_SCOPE_AGENT);
                if ((unsigned)v2 != want)
                    v2 = __hip_atomic_load(p2, __ATOMIC_RELAXED, __HIP_MEMORY_SCOPE_AGENT);
                if ((unsigned)v3 != want)
                    v3 = __hip_atomic_load(p3, __ATOMIC_RELAXED, __HIP_MEMORY_SCOPE_AGENT);
            }
            *(unsigned*)&h_lds[cm][((ng + 1) & 3) * 64 + 2 * cj] = (unsigned)(v1 >> 32);
            *(unsigned*)&h_lds[cm][((ng + 2) & 3) * 64 + 2 * cj] = (unsigned)(v2 >> 32);
            *(unsigned*)&h_lds[cm][((ng + 3) & 3) * 64 + 2 * cj] = (unsigned)(v3 >> 32);
            if (tid < 256)
                h_lds[tid >> 4][Hsz + (tid & 15)] = (_Float16)xr;
            __syncthreads();   // G4: full h_{t+1} + x_{t+1} staged
        }
    }
}

// ---------------- MLP head v7: NORMAL hh loads (NT-read throttle fix) ------
// Residue analysis: 44MB hh + 7GFLOP should be ~15us; measured ~55-65us
// = 0.7 TB/s. NT loads bypass L2/L3: ~900cy HBM latency x only 8x16B in
// flight/wave = latency-bound 0.6 TB/s — matches. v7: plain loads (an
// NT-written line read normally misses to HBM, allocates harmlessly —
// read-once, weights live in LDS) -> streaming path, ~6 TB/s ceiling.
// Structure otherwise = mlp6 (in-kernel swizzle, fully peeled 3 chunks).
__global__ __launch_bounds__(512, 2) void k_mlp7(
    const _Float16* __restrict__ hh, const float* __restrict__ fc1_w,
    const float* __restrict__ fc2_w, const float* __restrict__ b1,
    const float* __restrict__ b2, const float* __restrict__ w3,
    const float* __restrict__ b3, float* __restrict__ out) {
    __shared__ __align__(16) _Float16 w1sh[64 * 512];   // 64 KB
    __shared__ __align__(16) _Float16 w2sh[16 * 512];   // 16 KB
    __shared__ _Float16 st1[8][16][136];
    __shared__ _Float16 st2[8][16][72];

    const int tid = threadIdx.x;
    const int wave = tid >> 6, lane = tid & 63;
    const int n_in = lane & 15, quad = lane >> 4;

    {   // build fragment tables directly from fc1_w/fc2_w
#pragma unroll
        for (int it = 0; it < 8; ++it) {
            int s = it * 512 + tid;            // s = tile*64 + ln
            int tile = s >> 6, ln = s & 63;
            int nt = tile >> 3, kt = tile & 7, ni = ln & 15, kg = ln >> 4;
            const float* src = &fc1_w[(nt * 16 + ni) * 256 + kt * 32 + kg * 8];
            half8 v;
#pragma unroll
            for (int e = 0; e < 8; ++e) v[e] = (_Float16)src[e];
            ((half8*)w1sh)[s] = v;
        }
#pragma unroll
        for (int it = 0; it < 2; ++it) {
            int s = it * 512 + tid;
            int tile = s >> 6, ln = s & 63;
            int nt = tile >> 2, kt = tile & 3, ni = ln & 15, kg = ln >> 4;
            const float* src = &fc2_w[(nt * 16 + ni) * 128 + kt * 32 + kg * 8];
            half8 v;
#pragma unroll
            for (int e = 0; e < 8; ++e) v[e] = (_Float16)src[e];
            ((half8*)w2sh)[s] = v;
        }
    }
    __syncthreads();

    uint4v bufA[8], bufB[8], bufC[8];
    const int ch0 = blockIdx.x, ch1 = blockIdx.x + 224, ch2 = blockIdx.x + 448;

#define MLP_LOAD(dst, ch)                                                      \
    {                                                                          \
        const int tok0_ = (ch) * 128 + wave * 16;                              \
        _Pragma("unroll")                                                      \
        for (int kt = 0; kt < 8; ++kt)                                         \
            dst[kt] = *(const uint4v*)&hh[(size_t)(tok0_ + n_in) * 256 +       \
                                          kt * 32 + quad * 8];                 \
    }

    MLP_LOAD(bufA, ch0)
    MLP_LOAD(bufB, ch1)
    MLP_LOAD(bufC, ch2)

    auto compute = [&](const uint4v* raw, int chunk) {
        const int tok0 = chunk * 128 + wave * 16;
        half8 afr[8];
#pragma unroll
        for (int kt = 0; kt < 8; ++kt)
            afr[kt] = __builtin_bit_cast(half8, raw[kt]);

#pragma unroll
        for (int nt = 0; nt < 8; ++nt) {
            floatx4 a = (floatx4){0.f, 0.f, 0.f, 0.f};
#pragma unroll
            for (int kt = 0; kt < 8; ++kt) {
                half8 bfr = *(const half8*)&w1sh[(nt * 8 + kt) * 512 + lane * 8];
                a = __builtin_amdgcn_mfma_f32_16x16x32_f16(afr[kt], bfr, a, 0, 0, 0);
            }
            float bbv = b1[nt * 16 + n_in];
#pragma unroll
            for (int r = 0; r < 4; ++r) {
                float v = a[r] + bbv;
                st1[wave][quad * 4 + r][nt * 16 + n_in] = (_Float16)(v > 0.f ? v : 0.f);
            }
        }

        half8 a2[4];
#pragma unroll
        for (int kt = 0; kt < 4; ++kt)
            a2[kt] = *(const half8*)&st1[wave][n_in][kt * 32 + quad * 8];
#pragma unroll
        for (int nt = 0; nt < 4; ++nt) {
            floatx4 a = (floatx4){0.f, 0.f, 0.f, 0.f};
#pragma unroll
            for (int kt = 0; kt < 4; ++kt) {
                half8 bfr = *(const half8*)&w2sh[(nt * 4 + kt) * 512 + lane * 8];
                a = __builtin_amdgcn_mfma_f32_16x16x32_f16(a2[kt], bfr, a, 0, 0, 0);
            }
            float bbv = b2[nt * 16 + n_in];
#pragma unroll
            for (int r = 0; r < 4; ++r) {
                float v = a[r] + bbv;
                st2[wave][quad * 4 + r][nt * 16 + n_in] = (_Float16)(v > 0.f ? v : 0.f);
            }
        }

        float p = 0.0f;
#pragma unroll
        for (int e = 0; e < 16; ++e)
            p += (float)st2[wave][n_in][quad * 16 + e] * w3[quad * 16 + e];
        p += __shfl_down(p, 32);
        p += __shfl_down(p, 16);
        if (quad == 0) out[tok0 + n_in] = p + b3[0];
    };

    compute(bufA, ch0);
    compute(bufB, ch1);
    compute(bufC, ch2);
#undef MLP_LOAD
}

extern "C" void kernel_launch(void* const* d_in, const int* in_sizes, int n_in,
                              void* d_out, int out_size, void* d_ws, size_t ws_size,
                              hipStream_t stream) {
    const float* x     = (const float*)d_in[0];
    const float* w_ih  = (const float*)d_in[1];
    const float* w_hh  = (const float*)d_in[2];
    const float* b_ih  = (const float*)d_in[3];
    const float* b_hh  = (const float*)d_in[4];
    const float* fc1_w = (const float*)d_in[5];
    const float* fc1_b = (const float*)d_in[6];
    const float* fc2_w = (const float*)d_in[7];
    const float* fc2_b = (const float*)d_in[8];
    const float* fc3_w = (const float*)d_in[9];
    const float* fc3_b = (const float*)d_in[10];

    char* ws = (char*)d_ws;
    _Float16* wsw  = (_Float16*)(ws + WSW_OFF);
    float*    bias = (float*)(ws + BIAS_OFF);
    _Float16* hhist= (_Float16*)(ws + HH_OFF);
    unsigned long long* xbuf = (unsigned long long*)(ws + XBUF_OFF);

    k_prep<<<148, 256, 0, stream>>>(w_hh, w_ih, b_ih, b_hh, wsw, bias);
    k_lstm14<<<128, 512, 0, stream>>>(x, wsw, bias, (unsigned*)hhist, xbuf);
    k_mlp7<<<224, 512, 0, stream>>>(hhist, fc1_w, fc2_w, fc1_b, fc2_b,
                                    fc3_w, fc3_b, (float*)d_out);
}